// Round 8
// baseline (240.777 us; speedup 1.0000x reference)
//
#include <hip/hip_runtime.h>
#include <hip/hip_bf16.h>

// SoftmaxPermutationMatrix: out[b,x,y] = softmax_y(cos(xn,yn)/0.2) * mx[b,x] * my[b,y]
// Two-pass recompute scheme (scores bounded in [-5,5] => no max needed).
// R8: pass2 -> 8-y-tile loop per block with counted-vmcnt store overlap (T4):
//     per tile {barrier; stage Ys(t+1); issue 16 stores; s_waitcnt vmcnt(16);
//     barrier} so output stores stay in flight across the next tile's MFMA.
//     Breaks the phase-lock that serialized compute and store drain
//     (R6 measurement: pass2 = 127us = 45 compute + 82 write floor, 0 overlap).
//     masky in LDS (lgkm reads, no vmcnt interference). pass1 = R4 (45.4us).

typedef __attribute__((ext_vector_type(8))) short short8;
typedef __attribute__((ext_vector_type(4))) float float4v;

constexpr int B = 2, NX = 8192, NY = 8192, DD = 128;
constexpr int BM = 128, BN = 128;
constexpr int NSPLIT = 8;
constexpr int YCHUNK = NY / NSPLIT;   // 1024 (pass1)
constexpr int NTILE2 = 8;             // pass2 y-tiles per block
constexpr int YT2 = NTILE2 * BN;      // 1024
constexpr int ROWB = 256;             // bytes per LDS row (128 bf16, linear)
constexpr float TAU_INV = 5.0f;

__device__ __forceinline__ void gload16(const void* g, void* l) {
    __builtin_amdgcn_global_load_lds(
        (const __attribute__((address_space(1))) void*)g,
        (__attribute__((address_space(3))) void*)l, 16, 0, 0);
}

// Stage 128 rows x 256B from gsrc into lds (linear), content swizzled so that
// LDS(row, cb) = G(row, cb ^ ((row&7)<<4)). Each wave stages 32 rows.
__device__ __forceinline__ void stage_tile(const char* gsrc, char* lds, int wid, int lane) {
    const int srow = wid * 32;
    const int lr4 = lane >> 4;
    const int lcb = (lane & 15) * 16;
#pragma unroll
    for (int i = 0; i < 8; ++i) {
        int row = srow + i * 4 + lr4;
        int scb = lcb ^ ((row & 7) << 4);
        gload16(gsrc + (size_t)row * ROWB + scb, lds + (srow + i * 4) * ROWB);
    }
}

// ---------------- L2 normalize + cast to bf16 (one wave per 128-elem row) ----------------
__global__ __launch_bounds__(256) void l2norm_kernel(const float* __restrict__ in,
                                                     __hip_bfloat16* __restrict__ out,
                                                     int rows) {
    int wid = threadIdx.x >> 6, lane = threadIdx.x & 63;
    int row = blockIdx.x * 4 + wid;
    if (row >= rows) return;
    float2 v = ((const float2*)(in + (size_t)row * DD))[lane];
    float ss = v.x * v.x + v.y * v.y;
#pragma unroll
    for (int off = 32; off >= 1; off >>= 1) ss += __shfl_xor(ss, off);
    float inv = 1.0f / fmaxf(sqrtf(ss), 1e-12f);
    __hip_bfloat162 o;
    o.x = __float2bfloat16(v.x * inv);
    o.y = __float2bfloat16(v.y * inv);
    ((__hip_bfloat162*)(out + (size_t)row * DD))[lane] = o;
}

// ---------------- pass 1: per-x-row sum of exp(score) over a Ny chunk ----------------
__global__ __launch_bounds__(256) void pass1_kernel(const __hip_bfloat16* __restrict__ Xn,
                                                    const __hip_bfloat16* __restrict__ Yn,
                                                    float* __restrict__ partial) {
    __shared__ __hip_bfloat16 Xs[BM][DD];
    __shared__ __hip_bfloat16 Ys[BN][DD];
    const int split = blockIdx.x, xt = blockIdx.y, b = blockIdx.z;
    const int t = threadIdx.x;
    const int lane = t & 63, wid = t >> 6;
    const int wm = wid >> 1, wn = wid & 1;        // 2x2 waves, each 64x64 output
    const int lrow = lane & 15, lhi = lane >> 4;

    stage_tile((const char*)(Xn + (size_t)(b * NX + xt * BM) * DD), (char*)&Xs[0][0], wid, lane);

    float run[4][4];
#pragma unroll
    for (int m = 0; m < 4; ++m)
#pragma unroll
        for (int r = 0; r < 4; ++r) run[m][r] = 0.f;

    for (int tile = 0; tile < YCHUNK / BN; ++tile) {
        __syncthreads();
        stage_tile((const char*)(Yn + (size_t)(b * NY + split * YCHUNK + tile * BN) * DD),
                   (char*)&Ys[0][0], wid, lane);
        __syncthreads();

        float4v acc[4][4];
#pragma unroll
        for (int m = 0; m < 4; ++m)
#pragma unroll
            for (int n = 0; n < 4; ++n) acc[m][n] = (float4v)(0.f);
#pragma unroll
        for (int kk = 0; kk < 4; ++kk) {
            const int cb = (kk * 64 + lhi * 16) ^ ((lrow & 7) << 4);
            short8 a[4], bb[4];
#pragma unroll
            for (int m = 0; m < 4; ++m)
                a[m] = *(const short8*)((const char*)Xs + (size_t)(wm * 64 + m * 16 + lrow) * ROWB + cb);
#pragma unroll
            for (int n = 0; n < 4; ++n)
                bb[n] = *(const short8*)((const char*)Ys + (size_t)(wn * 64 + n * 16 + lrow) * ROWB + cb);
#pragma unroll
            for (int m = 0; m < 4; ++m)
#pragma unroll
                for (int n = 0; n < 4; ++n)
                    acc[m][n] = __builtin_amdgcn_mfma_f32_16x16x32_bf16(a[m], bb[n], acc[m][n], 0, 0, 0);
        }
#pragma unroll
        for (int m = 0; m < 4; ++m)
#pragma unroll
            for (int r = 0; r < 4; ++r) {
                float s = 0.f;
#pragma unroll
                for (int n = 0; n < 4; ++n) s += __expf(acc[m][n][r] * TAU_INV);
                run[m][r] += s;
            }
    }

#pragma unroll
    for (int m = 0; m < 4; ++m)
#pragma unroll
        for (int r = 0; r < 4; ++r) {
            float v = run[m][r];
            v += __shfl_xor(v, 1);
            v += __shfl_xor(v, 2);
            v += __shfl_xor(v, 4);
            v += __shfl_xor(v, 8);
            run[m][r] = v;
        }

    __syncthreads();
    float* lred = (float*)Ys;  // reuse LDS: [2][128]
    if (lrow == 0) {
#pragma unroll
        for (int m = 0; m < 4; ++m)
#pragma unroll
            for (int r = 0; r < 4; ++r) {
                int xl = wm * 64 + m * 16 + lhi * 4 + r;
                lred[wn * BM + xl] = run[m][r];
            }
    }
    __syncthreads();
    if (t < BM) {
        float tot = lred[t] + lred[BM + t];
        partial[(size_t)split * (B * NX) + (size_t)b * NX + xt * BM + t] = tot;
    }
}

// ---------------- combine partial sums -> rowscale = mask_x / sum ----------------
__global__ void combine_kernel(const float* __restrict__ partial,
                               const float* __restrict__ maskx,
                               float* __restrict__ rowscale) {
    int idx = blockIdx.x * 256 + threadIdx.x;
    if (idx >= B * NX) return;
    float s = 0.f;
#pragma unroll
    for (int i = 0; i < NSPLIT; ++i) s += partial[(size_t)i * (B * NX) + idx];
    rowscale[idx] = maskx[idx] / s;
}

// ---------------- pass 2: 8-tile loop, counted-vmcnt store overlap ----------------
__global__ __launch_bounds__(256) void pass2_kernel(const __hip_bfloat16* __restrict__ Xn,
                                                    const __hip_bfloat16* __restrict__ Yn,
                                                    const float* __restrict__ rowscale,
                                                    const float* __restrict__ masky,
                                                    float* __restrict__ out) {
    __shared__ char smem[32768 + 32768 + 4096];   // Xs + Ys + masky chunk
    char* XsB = smem;
    char* YsB = smem + 32768;
    char* MsB = smem + 65536;
    const int yt = blockIdx.x, xt = blockIdx.y, b = blockIdx.z;
    const int t = threadIdx.x;
    const int lane = t & 63, wid = t >> 6;
    const int wy = wid >> 1, wx = wid & 1;        // 2x2 waves, each 64y x 64x
    const int lrow = lane & 15, lhi = lane >> 4;

    const char* gy = (const char*)(Yn + (size_t)(b * NY + yt * YT2) * DD);

    // prologue: X tile (whole block lifetime), Y tile 0, masky chunk (4KB)
    stage_tile((const char*)(Xn + (size_t)(b * NX + xt * BM) * DD), XsB, wid, lane);
    stage_tile(gy, YsB, wid, lane);
    gload16((const char*)(masky + (size_t)b * NY + yt * YT2) + wid * 1024 + lane * 16,
            MsB + wid * 1024);
    float rs[4];
#pragma unroll
    for (int m = 0; m < 4; ++m)
        rs[m] = rowscale[(size_t)b * NX + xt * BM + wx * 64 + m * 16 + lrow];
    __syncthreads();   // full drain OK in prologue

    const int xbase = xt * BM + wx * 64;

#pragma unroll
    for (int tt = 0; tt < NTILE2; ++tt) {
        // ---- MFMA phase on Ys (tile tt) ----
        float4v acc[4][4];  // [n = y frag][m = x frag]
#pragma unroll
        for (int n = 0; n < 4; ++n)
#pragma unroll
            for (int m = 0; m < 4; ++m) acc[n][m] = (float4v)(0.f);
#pragma unroll
        for (int kk = 0; kk < 4; ++kk) {
            const int cb = (kk * 64 + lhi * 16) ^ ((lrow & 7) << 4);
            short8 a[4], bb[4];
#pragma unroll
            for (int n = 0; n < 4; ++n)
                a[n] = *(const short8*)(YsB + (size_t)(wy * 64 + n * 16 + lrow) * ROWB + cb);
#pragma unroll
            for (int m = 0; m < 4; ++m)
                bb[m] = *(const short8*)(XsB + (size_t)(wx * 64 + m * 16 + lrow) * ROWB + cb);
#pragma unroll
            for (int n = 0; n < 4; ++n)
#pragma unroll
                for (int m = 0; m < 4; ++m)
                    acc[n][m] = __builtin_amdgcn_mfma_f32_16x16x32_bf16(a[n], bb[m], acc[n][m], 0, 0, 0);
        }
        // masky for this tile from LDS (lgkm, no vmcnt interference)
        float4v my4[4];
#pragma unroll
        for (int n = 0; n < 4; ++n)
            my4[n] = *(const float4v*)(MsB + tt * 512 + wy * 256 + n * 64 + lhi * 16);

        __builtin_amdgcn_sched_barrier(0);
        __builtin_amdgcn_s_barrier();             // all waves done reading Ys(tt)
        __builtin_amdgcn_sched_barrier(0);

        if (tt + 1 < NTILE2)                      // restage Ys with tile tt+1 (8 gloads)
            stage_tile(gy + (size_t)(tt + 1) * BN * ROWB, YsB, wid, lane);
        __builtin_amdgcn_sched_barrier(0);        // pin: stage before stores in VMEM queue

        // ---- epilogue: 16 float4 stores, NOT waited ----
#pragma unroll
        for (int m = 0; m < 4; ++m) {
            const int x = xbase + m * 16 + lrow;
            float* orow = out + ((size_t)b * NX + x) * NY + yt * YT2 + tt * BN;
#pragma unroll
            for (int n = 0; n < 4; ++n) {
                float4v o;
#pragma unroll
                for (int r = 0; r < 4; ++r)
                    o[r] = __expf(acc[n][m][r] * TAU_INV) * rs[m] * my4[n][r];
                *(float4v*)(orow + wy * 64 + n * 16 + lhi * 4) = o;
            }
        }
        __builtin_amdgcn_sched_barrier(0);

        if (tt + 1 < NTILE2) {
            // retire staging (+old stores); keep this tile's 16 stores in flight
            asm volatile("s_waitcnt vmcnt(16)" ::: "memory");
            __builtin_amdgcn_sched_barrier(0);
            __builtin_amdgcn_s_barrier();         // staged Ys(tt+1) visible to all
            __builtin_amdgcn_sched_barrier(0);
        }
        // last tile: compiler drains vmcnt before endpgm
    }
}

extern "C" void kernel_launch(void* const* d_in, const int* in_sizes, int n_in,
                              void* d_out, int out_size, void* d_ws, size_t ws_size,
                              hipStream_t stream) {
    const float* feat_x = (const float*)d_in[0];
    const float* feat_y = (const float*)d_in[1];
    const float* maskx  = (const float*)d_in[2];
    const float* masky  = (const float*)d_in[3];
    float* out = (float*)d_out;

    char* ws = (char*)d_ws;
    __hip_bfloat16* Xn = (__hip_bfloat16*)ws;                                   // 4 MB
    __hip_bfloat16* Yn = (__hip_bfloat16*)(ws + (size_t)B * NX * DD * 2);       // 4 MB
    float* partial  = (float*)(ws + (size_t)B * (NX + NY) * DD * 2);            // 512 KB
    float* rowscale = partial + (size_t)NSPLIT * B * NX;                        // 64 KB

    l2norm_kernel<<<B * NX / 4, 256, 0, stream>>>(feat_x, Xn, B * NX);
    l2norm_kernel<<<B * NY / 4, 256, 0, stream>>>(feat_y, Yn, B * NY);
    pass1_kernel<<<dim3(NSPLIT, NX / BM, B), 256, 0, stream>>>(Xn, Yn, partial);
    combine_kernel<<<(B * NX + 255) / 256, 256, 0, stream>>>(partial, maskx, rowscale);
    pass2_kernel<<<dim3(NY / YT2, NX / BM, B), 256, 0, stream>>>(Xn, Yn, rowscale, masky, out);
}

// Round 9
// 198.066 us; speedup vs baseline: 1.2156x; 1.2156x over previous
//
#include <hip/hip_runtime.h>
#include <hip/hip_bf16.h>

// SoftmaxPermutationMatrix: out[b,x,y] = softmax_y(cos(xn,yn)/0.2) * mx[b,x] * my[b,y]
// Two-pass recompute scheme (scores bounded in [-5,5] => no max needed).
// R9: pass2 reverted to R7 (176.0us best; R8's vmcnt+sched_barrier store
//     pipeline regressed to 240.8). pass1 rebuilt as depth-2 counted-vmcnt
//     pipeline (T4 proper): 3 x BN1=64 Y-buffers (LDS 80KB, 2 blocks/CU),
//     stage(t+2) issued at iter t, s_waitcnt vmcnt(4) retires stage(t+1)
//     (issued one full iter earlier => ~zero wait). Load-only vmcnt queue =>
//     exact counts; no sched_barrier pinning (R8/m141 lesson).

typedef __attribute__((ext_vector_type(8))) short short8;
typedef __attribute__((ext_vector_type(4))) float float4v;

constexpr int B = 2, NX = 8192, NY = 8192, DD = 128;
constexpr int BM = 128, BN = 128;
constexpr int BN1 = 64;               // pass1 y-tile
constexpr int NSPLIT = 8;
constexpr int YCHUNK = NY / NSPLIT;   // 1024
constexpr int NT1 = YCHUNK / BN1;     // 16 y-tiles per pass1 block
constexpr int ROWB = 256;             // bytes per LDS row (128 bf16, linear)
constexpr float TAU_INV = 5.0f;

__device__ __forceinline__ void gload16(const void* g, void* l) {
    __builtin_amdgcn_global_load_lds(
        (const __attribute__((address_space(1))) void*)g,
        (__attribute__((address_space(3))) void*)l, 16, 0, 0);
}

// Stage NR rows x 256B from gsrc into lds (linear), content swizzled so that
// LDS(row, cb) = G(row, cb ^ ((row&7)<<4)). 4 waves share the NR rows.
template<int NR>
__device__ __forceinline__ void stage_rows(const char* gsrc, char* lds, int wid, int lane) {
    constexpr int RPW = NR / 4;           // rows per wave
    const int srow = wid * RPW;
    const int lr4 = lane >> 4;            // 0..3
    const int lcb = (lane & 15) * 16;
#pragma unroll
    for (int i = 0; i < RPW; i += 4) {
        int row = srow + i + lr4;
        int scb = lcb ^ ((row & 7) << 4);
        gload16(gsrc + (size_t)row * ROWB + scb, lds + (size_t)(srow + i) * ROWB);
    }
}

// ---------------- L2 normalize + cast to bf16 (one wave per 128-elem row) ----------------
__global__ __launch_bounds__(256) void l2norm_kernel(const float* __restrict__ in,
                                                     __hip_bfloat16* __restrict__ out,
                                                     int rows) {
    int wid = threadIdx.x >> 6, lane = threadIdx.x & 63;
    int row = blockIdx.x * 4 + wid;
    if (row >= rows) return;
    float2 v = ((const float2*)(in + (size_t)row * DD))[lane];
    float ss = v.x * v.x + v.y * v.y;
#pragma unroll
    for (int off = 32; off >= 1; off >>= 1) ss += __shfl_xor(ss, off);
    float inv = 1.0f / fmaxf(sqrtf(ss), 1e-12f);
    __hip_bfloat162 o;
    o.x = __float2bfloat16(v.x * inv);
    o.y = __float2bfloat16(v.y * inv);
    ((__hip_bfloat162*)(out + (size_t)row * DD))[lane] = o;
}

// ---------------- pass 1: per-x-row sum of exp(score), depth-2 counted-vmcnt ----------------
__global__ __launch_bounds__(256) void pass1_kernel(const __hip_bfloat16* __restrict__ Xn,
                                                    const __hip_bfloat16* __restrict__ Yn,
                                                    float* __restrict__ partial) {
    __shared__ char Xs[BM * ROWB];            // 32KB
    __shared__ char Ys[3][BN1 * ROWB];        // 3 x 16KB
    const int split = blockIdx.x, xt = blockIdx.y, b = blockIdx.z;
    const int t = threadIdx.x;
    const int lane = t & 63, wid = t >> 6;
    const int wm = wid >> 1, wn = wid & 1;    // wave tile: 64x x 32y
    const int lrow = lane & 15, lhi = lane >> 4;

    const char* gy0 = (const char*)(Yn + (size_t)(b * NY + split * YCHUNK) * DD);

    // prologue: X (8 loads/wave), Y0 (4), Y1 (4) -> 16 outstanding
    stage_rows<BM>((const char*)(Xn + (size_t)(b * NX + xt * BM) * DD), Xs, wid, lane);
    stage_rows<BN1>(gy0, Ys[0], wid, lane);
    stage_rows<BN1>(gy0 + (size_t)BN1 * ROWB, Ys[1], wid, lane);
    asm volatile("s_waitcnt vmcnt(4)" ::: "memory");   // X + Y0 landed; Y1 may fly
    __builtin_amdgcn_s_barrier();

    float run[4][4];
#pragma unroll
    for (int m = 0; m < 4; ++m)
#pragma unroll
        for (int r = 0; r < 4; ++r) run[m][r] = 0.f;

#pragma unroll
    for (int tile = 0; tile < NT1; ++tile) {
        if (tile + 2 < NT1)                   // depth-2 prefetch (4 loads/wave)
            stage_rows<BN1>(gy0 + (size_t)(tile + 2) * BN1 * ROWB,
                            Ys[(tile + 2) % 3], wid, lane);

        const char* ycur = Ys[tile % 3];
        float4v acc[4][2];
#pragma unroll
        for (int m = 0; m < 4; ++m)
#pragma unroll
            for (int n = 0; n < 2; ++n) acc[m][n] = (float4v)(0.f);
#pragma unroll
        for (int kk = 0; kk < 4; ++kk) {
            const int cb = (kk * 64 + lhi * 16) ^ ((lrow & 7) << 4);
            short8 a[4], bb[2];
#pragma unroll
            for (int m = 0; m < 4; ++m)
                a[m] = *(const short8*)(Xs + (size_t)(wm * 64 + m * 16 + lrow) * ROWB + cb);
#pragma unroll
            for (int n = 0; n < 2; ++n)
                bb[n] = *(const short8*)(ycur + (size_t)(wn * 32 + n * 16 + lrow) * ROWB + cb);
#pragma unroll
            for (int m = 0; m < 4; ++m)
#pragma unroll
                for (int n = 0; n < 2; ++n)
                    acc[m][n] = __builtin_amdgcn_mfma_f32_16x16x32_bf16(a[m], bb[n], acc[m][n], 0, 0, 0);
        }
#pragma unroll
        for (int m = 0; m < 4; ++m)
#pragma unroll
            for (int r = 0; r < 4; ++r) {
                float s = __expf(acc[m][0][r] * TAU_INV) + __expf(acc[m][1][r] * TAU_INV);
                run[m][r] += s;
            }

        if (tile + 1 < NT1) {
            if (tile + 2 < NT1)
                asm volatile("s_waitcnt vmcnt(4)" ::: "memory");  // retire stage(t+1)
            else
                asm volatile("s_waitcnt vmcnt(0)" ::: "memory");  // last staged buffer
            __builtin_amdgcn_s_barrier();
        }
    }

    // butterfly across the 16 lanes sharing the same x (low 4 lane bits = y cols)
#pragma unroll
    for (int m = 0; m < 4; ++m)
#pragma unroll
        for (int r = 0; r < 4; ++r) {
            float v = run[m][r];
            v += __shfl_xor(v, 1);
            v += __shfl_xor(v, 2);
            v += __shfl_xor(v, 4);
            v += __shfl_xor(v, 8);
            run[m][r] = v;
        }

    __syncthreads();
    float* lred = (float*)Xs;  // reuse X LDS: [2][128] floats
    if (lrow == 0) {
#pragma unroll
        for (int m = 0; m < 4; ++m)
#pragma unroll
            for (int r = 0; r < 4; ++r) {
                int xl = wm * 64 + m * 16 + lhi * 4 + r;
                lred[wn * BM + xl] = run[m][r];
            }
    }
    __syncthreads();
    if (t < BM) {
        float tot = lred[t] + lred[BM + t];
        partial[(size_t)split * (B * NX) + (size_t)b * NX + xt * BM + t] = tot;
    }
}

// ---------------- combine partial sums -> rowscale = mask_x / sum ----------------
__global__ void combine_kernel(const float* __restrict__ partial,
                               const float* __restrict__ maskx,
                               float* __restrict__ rowscale) {
    int idx = blockIdx.x * 256 + threadIdx.x;
    if (idx >= B * NX) return;
    float s = 0.f;
#pragma unroll
    for (int i = 0; i < NSPLIT; ++i) s += partial[(size_t)i * (B * NX) + idx];
    rowscale[idx] = maskx[idx] / s;
}

// ---------------- pass 2: R7 version (LDS-staged GEMM + LDS-transpose epilogue) ----------
__global__ __launch_bounds__(256) void pass2_kernel(const __hip_bfloat16* __restrict__ Xn,
                                                    const __hip_bfloat16* __restrict__ Yn,
                                                    const float* __restrict__ rowscale,
                                                    const float* __restrict__ masky,
                                                    float* __restrict__ out) {
    __shared__ char smem[65536];
    char* XsB = smem;            // 32KB bf16 [128][128]
    char* YsB = smem + 32768;    // 32KB
    const int yt = blockIdx.x, xt = blockIdx.y, b = blockIdx.z;
    const int t = threadIdx.x;
    const int lane = t & 63, wid = t >> 6;
    const int wy = wid >> 1, wx = wid & 1;        // 2x2 waves, each 64y x 64x
    const int lrow = lane & 15, lhi = lane >> 4;

    {   // stage via gload_lds (8 loads/wave each)
        const int srow = wid * 32;
        const int lr4 = lane >> 4;
        const int lcb = (lane & 15) * 16;
        const char* gx = (const char*)(Xn + (size_t)(b * NX + xt * BM) * DD);
        const char* gy = (const char*)(Yn + (size_t)(b * NY + yt * BN) * DD);
#pragma unroll
        for (int i = 0; i < 8; ++i) {
            int row = srow + i * 4 + lr4;
            int scb = lcb ^ ((row & 7) << 4);
            gload16(gx + (size_t)row * ROWB + scb, XsB + (srow + i * 4) * ROWB);
            gload16(gy + (size_t)row * ROWB + scb, YsB + (srow + i * 4) * ROWB);
        }
    }
    __syncthreads();

    float4v acc[4][4];  // [n = y frag][m = x frag]
#pragma unroll
    for (int n = 0; n < 4; ++n)
#pragma unroll
        for (int m = 0; m < 4; ++m) acc[n][m] = (float4v)(0.f);

#pragma unroll
    for (int kk = 0; kk < 4; ++kk) {
        const int cb = (kk * 64 + lhi * 16) ^ ((lrow & 7) << 4);
        short8 a[4], bb[4];
#pragma unroll
        for (int n = 0; n < 4; ++n)
            a[n] = *(const short8*)(YsB + (size_t)(wy * 64 + n * 16 + lrow) * ROWB + cb);
#pragma unroll
        for (int m = 0; m < 4; ++m)
            bb[m] = *(const short8*)(XsB + (size_t)(wx * 64 + m * 16 + lrow) * ROWB + cb);
#pragma unroll
        for (int n = 0; n < 4; ++n)
#pragma unroll
            for (int m = 0; m < 4; ++m)
                acc[n][m] = __builtin_amdgcn_mfma_f32_16x16x32_bf16(a[n], bb[m], acc[n][m], 0, 0, 0);
    }

    const int ybase = yt * BN + wy * 64;
    const int xbase = xt * BM + wx * 64;

    float rs[4];
#pragma unroll
    for (int m = 0; m < 4; ++m)
        rs[m] = rowscale[(size_t)b * NX + xbase + m * 16 + lrow];
    float4v my4[4];
#pragma unroll
    for (int n = 0; n < 4; ++n)
        my4[n] = *(const float4v*)(masky + (size_t)b * NY + ybase + n * 16 + lhi * 4);

    __syncthreads();   // all waves done reading Xs/Ys; smem becomes out-tile

    // write phase: tile[x][ybytes ^ ((x&7)<<4)], x-row = 512B
#pragma unroll
    for (int m = 0; m < 4; ++m) {
        const int xl = wx * 64 + m * 16 + lrow;
#pragma unroll
        for (int n = 0; n < 4; ++n) {
            float4v o;
#pragma unroll
            for (int r = 0; r < 4; ++r)
                o[r] = __expf(acc[n][m][r] * TAU_INV) * rs[m] * my4[n][r];
            const int yb = wy * 256 + n * 64 + lhi * 16;   // byte offset in 512B row
            *(float4v*)(smem + (size_t)xl * 512 + (yb ^ ((xl & 7) << 4))) = o;
        }
    }
    __syncthreads();

    // store phase: each instruction = 2 complete 512B row-segments (full lines)
    const int halfl = lane >> 5, l31 = lane & 31;
    const size_t orow0 = ((size_t)b * NX + xt * BM) * NY + yt * BN;
#pragma unroll
    for (int s = 0; s < 16; ++s) {
        const int xr = wid * 32 + s * 2 + halfl;
        float4v v = *(const float4v*)(smem + (size_t)xr * 512 + ((l31 * 16) ^ ((xr & 7) << 4)));
        *(float4v*)(out + orow0 + (size_t)xr * NY + l31 * 4) = v;
    }
}

extern "C" void kernel_launch(void* const* d_in, const int* in_sizes, int n_in,
                              void* d_out, int out_size, void* d_ws, size_t ws_size,
                              hipStream_t stream) {
    const float* feat_x = (const float*)d_in[0];
    const float* feat_y = (const float*)d_in[1];
    const float* maskx  = (const float*)d_in[2];
    const float* masky  = (const float*)d_in[3];
    float* out = (float*)d_out;

    char* ws = (char*)d_ws;
    __hip_bfloat16* Xn = (__hip_bfloat16*)ws;                                   // 4 MB
    __hip_bfloat16* Yn = (__hip_bfloat16*)(ws + (size_t)B * NX * DD * 2);       // 4 MB
    float* partial  = (float*)(ws + (size_t)B * (NX + NY) * DD * 2);            // 512 KB
    float* rowscale = partial + (size_t)NSPLIT * B * NX;                        // 64 KB

    l2norm_kernel<<<B * NX / 4, 256, 0, stream>>>(feat_x, Xn, B * NX);
    l2norm_kernel<<<B * NY / 4, 256, 0, stream>>>(feat_y, Yn, B * NY);
    pass1_kernel<<<dim3(NSPLIT, NX / BM, B), 256, 0, stream>>>(Xn, Yn, partial);
    combine_kernel<<<(B * NX + 255) / 256, 256, 0, stream>>>(partial, maskx, rowscale);
    pass2_kernel<<<dim3(NY / BN, NX / BM, B), 256, 0, stream>>>(Xn, Yn, rowscale, masky, out);
}

// Round 10
// 188.123 us; speedup vs baseline: 1.2799x; 1.0529x over previous
//
#include <hip/hip_runtime.h>
#include <hip/hip_bf16.h>

// SoftmaxPermutationMatrix: out[b,x,y] = softmax_y(cos(xn,yn)/0.2) * mx[b,x] * my[b,y]
// Two-pass recompute scheme (scores bounded in [-5,5] => no max needed).
// R10: pass1 reverted to R4 (45.4us measured; R9's depth-2 vmcnt pipeline
//      regressed it to ~67). pass2: minimal store/compute interleave -- per
//      y-quadrant {4 ds_read, 16 MFMA, exp, 4 direct float4 stores,
//      sched_barrier(0)} so the write pipe is fed during ~75% of compute
//      instead of bursting at block end (R6: pass2 = 45 compute + 82 writes,
//      zero overlap). No vmcnt asm, no extra barriers (R8/R9 lessons).

typedef __attribute__((ext_vector_type(8))) short short8;
typedef __attribute__((ext_vector_type(4))) float float4v;

constexpr int B = 2, NX = 8192, NY = 8192, DD = 128;
constexpr int BM = 128, BN = 128;
constexpr int NSPLIT = 8;
constexpr int YCHUNK = NY / NSPLIT;   // 1024
constexpr int ROWB = 256;             // bytes per LDS row (128 bf16, linear)
constexpr float TAU_INV = 5.0f;

__device__ __forceinline__ void gload16(const void* g, void* l) {
    __builtin_amdgcn_global_load_lds(
        (const __attribute__((address_space(1))) void*)g,
        (__attribute__((address_space(3))) void*)l, 16, 0, 0);
}

// Stage 128 rows x 256B from gsrc into lds (linear), content swizzled so that
// LDS(row, cb) = G(row, cb ^ ((row&7)<<4)). Each wave stages 32 rows.
__device__ __forceinline__ void stage_tile(const char* gsrc, char* lds, int wid, int lane) {
    const int srow = wid * 32;
    const int lr4 = lane >> 4;
    const int lcb = (lane & 15) * 16;
#pragma unroll
    for (int i = 0; i < 8; ++i) {
        int row = srow + i * 4 + lr4;
        int scb = lcb ^ ((row & 7) << 4);
        gload16(gsrc + (size_t)row * ROWB + scb, lds + (srow + i * 4) * ROWB);
    }
}

// ---------------- L2 normalize + cast to bf16 (one wave per 128-elem row) ----------------
__global__ __launch_bounds__(256) void l2norm_kernel(const float* __restrict__ in,
                                                     __hip_bfloat16* __restrict__ out,
                                                     int rows) {
    int wid = threadIdx.x >> 6, lane = threadIdx.x & 63;
    int row = blockIdx.x * 4 + wid;
    if (row >= rows) return;
    float2 v = ((const float2*)(in + (size_t)row * DD))[lane];
    float ss = v.x * v.x + v.y * v.y;
#pragma unroll
    for (int off = 32; off >= 1; off >>= 1) ss += __shfl_xor(ss, off);
    float inv = 1.0f / fmaxf(sqrtf(ss), 1e-12f);
    __hip_bfloat162 o;
    o.x = __float2bfloat16(v.x * inv);
    o.y = __float2bfloat16(v.y * inv);
    ((__hip_bfloat162*)(out + (size_t)row * DD))[lane] = o;
}

// ---------------- pass 1: per-x-row sum of exp(score) over a Ny chunk (R4) ----------------
__global__ __launch_bounds__(256) void pass1_kernel(const __hip_bfloat16* __restrict__ Xn,
                                                    const __hip_bfloat16* __restrict__ Yn,
                                                    float* __restrict__ partial) {
    __shared__ __hip_bfloat16 Xs[BM][DD];
    __shared__ __hip_bfloat16 Ys[BN][DD];
    const int split = blockIdx.x, xt = blockIdx.y, b = blockIdx.z;
    const int t = threadIdx.x;
    const int lane = t & 63, wid = t >> 6;
    const int wm = wid >> 1, wn = wid & 1;        // 2x2 waves, each 64x64 output
    const int lrow = lane & 15, lhi = lane >> 4;

    stage_tile((const char*)(Xn + (size_t)(b * NX + xt * BM) * DD), (char*)&Xs[0][0], wid, lane);

    float run[4][4];
#pragma unroll
    for (int m = 0; m < 4; ++m)
#pragma unroll
        for (int r = 0; r < 4; ++r) run[m][r] = 0.f;

    for (int tile = 0; tile < YCHUNK / BN; ++tile) {
        __syncthreads();
        stage_tile((const char*)(Yn + (size_t)(b * NY + split * YCHUNK + tile * BN) * DD),
                   (char*)&Ys[0][0], wid, lane);
        __syncthreads();

        float4v acc[4][4];
#pragma unroll
        for (int m = 0; m < 4; ++m)
#pragma unroll
            for (int n = 0; n < 4; ++n) acc[m][n] = (float4v)(0.f);
#pragma unroll
        for (int kk = 0; kk < 4; ++kk) {
            const int cb = (kk * 64 + lhi * 16) ^ ((lrow & 7) << 4);
            short8 a[4], bb[4];
#pragma unroll
            for (int m = 0; m < 4; ++m)
                a[m] = *(const short8*)((const char*)Xs + (size_t)(wm * 64 + m * 16 + lrow) * ROWB + cb);
#pragma unroll
            for (int n = 0; n < 4; ++n)
                bb[n] = *(const short8*)((const char*)Ys + (size_t)(wn * 64 + n * 16 + lrow) * ROWB + cb);
#pragma unroll
            for (int m = 0; m < 4; ++m)
#pragma unroll
                for (int n = 0; n < 4; ++n)
                    acc[m][n] = __builtin_amdgcn_mfma_f32_16x16x32_bf16(a[m], bb[n], acc[m][n], 0, 0, 0);
        }
#pragma unroll
        for (int m = 0; m < 4; ++m)
#pragma unroll
            for (int r = 0; r < 4; ++r) {
                float s = 0.f;
#pragma unroll
                for (int n = 0; n < 4; ++n) s += __expf(acc[m][n][r] * TAU_INV);
                run[m][r] += s;
            }
    }

#pragma unroll
    for (int m = 0; m < 4; ++m)
#pragma unroll
        for (int r = 0; r < 4; ++r) {
            float v = run[m][r];
            v += __shfl_xor(v, 1);
            v += __shfl_xor(v, 2);
            v += __shfl_xor(v, 4);
            v += __shfl_xor(v, 8);
            run[m][r] = v;
        }

    __syncthreads();
    float* lred = (float*)Ys;  // reuse LDS: [2][128]
    if (lrow == 0) {
#pragma unroll
        for (int m = 0; m < 4; ++m)
#pragma unroll
            for (int r = 0; r < 4; ++r) {
                int xl = wm * 64 + m * 16 + lhi * 4 + r;
                lred[wn * BM + xl] = run[m][r];
            }
    }
    __syncthreads();
    if (t < BM) {
        float tot = lred[t] + lred[BM + t];
        partial[(size_t)split * (B * NX) + (size_t)b * NX + xt * BM + t] = tot;
    }
}

// ---------------- combine partial sums -> rowscale = mask_x / sum ----------------
__global__ void combine_kernel(const float* __restrict__ partial,
                               const float* __restrict__ maskx,
                               float* __restrict__ rowscale) {
    int idx = blockIdx.x * 256 + threadIdx.x;
    if (idx >= B * NX) return;
    float s = 0.f;
#pragma unroll
    for (int i = 0; i < NSPLIT; ++i) s += partial[(size_t)i * (B * NX) + idx];
    rowscale[idx] = maskx[idx] / s;
}

// ---------------- pass 2: per-quadrant interleaved MFMA + stores ----------------
// mfma(Yfrag, Xfrag) -> D[row=y, col=x]; lane holds 4 consecutive y for one x.
// X fragments held in registers (bb[4][4]); per y-quadrant n: 4 ds_read,
// 16 MFMA, exp+mask, 4 direct float4 stores. sched_barrier(0) between
// quadrants prevents store-sinking to the block end.
__global__ __launch_bounds__(256) void pass2_kernel(const __hip_bfloat16* __restrict__ Xn,
                                                    const __hip_bfloat16* __restrict__ Yn,
                                                    const float* __restrict__ rowscale,
                                                    const float* __restrict__ masky,
                                                    float* __restrict__ out) {
    __shared__ char XsB[BM * ROWB];   // 32KB
    __shared__ char YsB[BN * ROWB];   // 32KB
    const int yt = blockIdx.x, xt = blockIdx.y, b = blockIdx.z;
    const int t = threadIdx.x;
    const int lane = t & 63, wid = t >> 6;
    const int wy = wid >> 1, wx = wid & 1;        // 2x2 waves, each 64y x 64x
    const int lrow = lane & 15, lhi = lane >> 4;

    stage_tile((const char*)(Xn + (size_t)(b * NX + xt * BM) * DD), XsB, wid, lane);
    stage_tile((const char*)(Yn + (size_t)(b * NY + yt * BN) * DD), YsB, wid, lane);

    const int ybase = yt * BN + wy * 64;
    const int xbase = xt * BM + wx * 64;

    float rs[4];
#pragma unroll
    for (int m = 0; m < 4; ++m)
        rs[m] = rowscale[(size_t)b * NX + xbase + m * 16 + lrow];
    float4v my4[4];
#pragma unroll
    for (int n = 0; n < 4; ++n)
        my4[n] = *(const float4v*)(masky + (size_t)b * NY + ybase + n * 16 + lhi * 4);

    __syncthreads();

    // all X fragments into registers: bb[m][kk]
    short8 bb[4][4];
#pragma unroll
    for (int kk = 0; kk < 4; ++kk) {
        const int cb = (kk * 64 + lhi * 16) ^ ((lrow & 7) << 4);
#pragma unroll
        for (int m = 0; m < 4; ++m)
            bb[m][kk] = *(const short8*)(XsB + (size_t)(wx * 64 + m * 16 + lrow) * ROWB + cb);
    }

#pragma unroll
    for (int n = 0; n < 4; ++n) {
        // Y fragments for this quadrant
        short8 a[4];
#pragma unroll
        for (int kk = 0; kk < 4; ++kk) {
            const int cb = (kk * 64 + lhi * 16) ^ ((lrow & 7) << 4);
            a[kk] = *(const short8*)(YsB + (size_t)(wy * 64 + n * 16 + lrow) * ROWB + cb);
        }
        float4v acc[4];
#pragma unroll
        for (int m = 0; m < 4; ++m) acc[m] = (float4v)(0.f);
#pragma unroll
        for (int kk = 0; kk < 4; ++kk)
#pragma unroll
            for (int m = 0; m < 4; ++m)
                acc[m] = __builtin_amdgcn_mfma_f32_16x16x32_bf16(a[kk], bb[m][kk], acc[m], 0, 0, 0);

        // quadrant epilogue: exp, mask, store NOW (feeds the write pipe early)
#pragma unroll
        for (int m = 0; m < 4; ++m) {
            const int x = xbase + m * 16 + lrow;
            float* orow = out + ((size_t)b * NX + x) * NY;
            float4v o;
#pragma unroll
            for (int r = 0; r < 4; ++r)
                o[r] = __expf(acc[m][r] * TAU_INV) * rs[m] * my4[n][r];
            *(float4v*)(orow + ybase + n * 16 + lhi * 4) = o;
        }
        __builtin_amdgcn_sched_barrier(0);   // keep this quadrant's stores here
    }
}

extern "C" void kernel_launch(void* const* d_in, const int* in_sizes, int n_in,
                              void* d_out, int out_size, void* d_ws, size_t ws_size,
                              hipStream_t stream) {
    const float* feat_x = (const float*)d_in[0];
    const float* feat_y = (const float*)d_in[1];
    const float* maskx  = (const float*)d_in[2];
    const float* masky  = (const float*)d_in[3];
    float* out = (float*)d_out;

    char* ws = (char*)d_ws;
    __hip_bfloat16* Xn = (__hip_bfloat16*)ws;                                   // 4 MB
    __hip_bfloat16* Yn = (__hip_bfloat16*)(ws + (size_t)B * NX * DD * 2);       // 4 MB
    float* partial  = (float*)(ws + (size_t)B * (NX + NY) * DD * 2);            // 512 KB
    float* rowscale = partial + (size_t)NSPLIT * B * NX;                        // 64 KB

    l2norm_kernel<<<B * NX / 4, 256, 0, stream>>>(feat_x, Xn, B * NX);
    l2norm_kernel<<<B * NY / 4, 256, 0, stream>>>(feat_y, Yn, B * NY);
    pass1_kernel<<<dim3(NSPLIT, NX / BM, B), 256, 0, stream>>>(Xn, Yn, partial);
    combine_kernel<<<(B * NX + 255) / 256, 256, 0, stream>>>(partial, maskx, rowscale);
    pass2_kernel<<<dim3(NY / BN, NX / BM, B), 256, 0, stream>>>(Xn, Yn, rowscale, masky, out);
}